// Round 11
// baseline (151.201 us; speedup 1.0000x reference)
//
#include <hip/hip_runtime.h>
#include <hip/hip_bf16.h>
#include <cstdint>

#define TT 2048
#define HD 64
#define NH 16
#define CDIM 1024
#define N3 3072
#define BT 4096
#define QSCALE 0.18033688011112042f  // 0.125 * log2(e)

using bf16 = __hip_bfloat16;
typedef __attribute__((ext_vector_type(4))) float f32x4;
typedef __attribute__((ext_vector_type(8))) short short8;
typedef __attribute__((ext_vector_type(8))) __bf16 bf16x8v;

__device__ __forceinline__ short f2bbits(float f) {
  __hip_bfloat16 h = __float2bfloat16(f);
  return __builtin_bit_cast(short, h);
}

__device__ __forceinline__ f32x4 mfma_bf16(short8 a, short8 b, f32x4 c) {
  return __builtin_amdgcn_mfma_f32_16x16x32_bf16(
      __builtin_bit_cast(bf16x8v, a), __builtin_bit_cast(bf16x8v, b), c, 0, 0, 0);
}

__device__ __forceinline__ void gll16(const void* g, void* l) {
  __builtin_amdgcn_global_load_lds(
      (const __attribute__((address_space(1))) void*)g,
      (__attribute__((address_space(3))) void*)l, 16, 0, 0);
}

// v_exp_f32 computes 2^x
__device__ __forceinline__ float exp2_fast(float x) {
  float r;
  asm("v_exp_f32 %0, %1" : "=v"(r) : "v"(x));
  return r;
}

// pack two f32 -> one u32 of 2 bf16 (lo = first arg), RNE
__device__ __forceinline__ uint32_t pkbf16(float lo, float hi) {
  uint32_t lw = (uint32_t)(uint16_t)f2bbits(lo);
  uint32_t hw = (uint32_t)(uint16_t)f2bbits(hi);
  return (hw << 16) | lw;
}

// ---------------- prep kernels ----------------

__global__ __launch_bounds__(256) void cvt_f32_to_bf16(const float* __restrict__ in,
                                                       bf16* __restrict__ out, int n) {
  int idx = (blockIdx.x * 256 + threadIdx.x) * 8;
  if (idx >= n) return;
  float4 a = *(const float4*)(in + idx);
  float4 b = *(const float4*)(in + idx + 4);
  short8 o;
  o[0] = f2bbits(a.x); o[1] = f2bbits(a.y); o[2] = f2bbits(a.z); o[3] = f2bbits(a.w);
  o[4] = f2bbits(b.x); o[5] = f2bbits(b.y); o[6] = f2bbits(b.z); o[7] = f2bbits(b.w);
  *(short8*)(out + idx) = o;
}

// in [R][C] fp32 -> out [C][R] bf16
__global__ __launch_bounds__(256) void transpose_to_bf16(const float* __restrict__ in,
                                                         bf16* __restrict__ out,
                                                         int R, int C) {
  __shared__ float tile[32][33];
  int c0 = blockIdx.x * 32, r0 = blockIdx.y * 32;
  int tx = threadIdx.x, ty = threadIdx.y;  // 32 x 8
#pragma unroll
  for (int i = 0; i < 32; i += 8)
    tile[ty + i][tx] = in[(size_t)(r0 + ty + i) * C + c0 + tx];
  __syncthreads();
#pragma unroll
  for (int i = 0; i < 32; i += 8)
    out[(size_t)(c0 + ty + i) * R + r0 + tx] = __float2bfloat16(tile[tx][ty + i]);
}

__global__ __launch_bounds__(256) void rope_table(float* __restrict__ cost,
                                                  float* __restrict__ sint) {
  int idx = blockIdx.x * 256 + threadIdx.x;  // t*32 + i, 65536 total
  int t = idx >> 5, i = idx & 31;
  double inv = exp(-(double)i / 32.0 * log(10000.0));
  double a = (double)t * inv;
  cost[idx] = (float)cos(a);
  sint[idx] = (float)sin(a);
}

// V [bh][T][64] -> VT [bh][64][T]
__global__ __launch_bounds__(256) void transpose_v(const bf16* __restrict__ V,
                                                   bf16* __restrict__ VT) {
  __shared__ bf16 tile[32][33];
  int bh = blockIdx.z;
  int t0 = blockIdx.x * 32, d0 = blockIdx.y * 32;
  const bf16* src = V + (size_t)bh * TT * HD;
  bf16* dst = VT + (size_t)bh * TT * HD;
  int tx = threadIdx.x, ty = threadIdx.y;
#pragma unroll
  for (int i = 0; i < 32; i += 8)
    tile[ty + i][tx] = src[(size_t)(t0 + ty + i) * HD + d0 + tx];
  __syncthreads();
#pragma unroll
  for (int i = 0; i < 32; i += 8)
    dst[(size_t)(d0 + ty + i) * TT + t0 + tx] = tile[tx][ty + i];
}

// ---------------- GEMM core: C[128x128] = A[128xK] * Bt[128xK]^T ----------------
// BK=64, XOR-swizzled LDS (pre-swizzled global source chunks, linear gll16 dest,
// swizzled ds_read). 256 threads, 4 waves (2x2 of 64x64 sub-tiles).

__device__ __forceinline__ void gemm_core(const bf16* __restrict__ A, const bf16* __restrict__ Bt,
                                          int K, int m0, int n0, f32x4 acc[4][4],
                                          bf16* As, bf16* Bs) {
  int tid = threadIdx.x;
  int w = tid >> 6, l = tid & 63;
  int wm = (w >> 1) * 64, wn = (w & 1) * 64;
  for (int kt = 0; kt < K; kt += 64) {
#pragma unroll
    for (int it = 0; it < 4; ++it) {
      int ci = it * 256 + tid;            // 0..1023 chunk index (16B chunks)
      int r = ci >> 3, cc = ci & 7;
      int sc = cc ^ (r & 7);              // pre-swizzled source chunk
      gll16(A + (size_t)(m0 + r) * K + kt + sc * 8, As + (it * 256 + w * 64) * 8);
      gll16(Bt + (size_t)(n0 + r) * K + kt + sc * 8, Bs + (it * 256 + w * 64) * 8);
    }
    __syncthreads();
#pragma unroll
    for (int c = 0; c < 2; ++c) {
      short8 af[4], bfr[4];
#pragma unroll
      for (int i = 0; i < 4; ++i) {
        int row = wm + i * 16 + (l & 15);
        int colE = c * 32 + (l >> 4) * 8;
        af[i] = *(const short8*)(As + row * 64 + (colE ^ ((row & 7) << 3)));
      }
#pragma unroll
      for (int j = 0; j < 4; ++j) {
        int row = wn + j * 16 + (l & 15);
        int colE = c * 32 + (l >> 4) * 8;
        bfr[j] = *(const short8*)(Bs + row * 64 + (colE ^ ((row & 7) << 3)));
      }
#pragma unroll
      for (int i = 0; i < 4; ++i)
#pragma unroll
        for (int j = 0; j < 4; ++j)
          acc[i][j] = mfma_bf16(af[i], bfr[j], acc[i][j]);
    }
    __syncthreads();
  }
}

// QKV GEMM: x[4096][1024] @ Wqkv -> Q/K/V [bh][t][64] bf16, RoPE fused for Q,K.
// Q additionally pre-scaled by QSCALE so attn softmax is exp2(s) directly.
__global__ __launch_bounds__(256) void qkv_gemm(const bf16* __restrict__ xb,
                                                const bf16* __restrict__ WqkvT,
                                                const float* __restrict__ cost,
                                                const float* __restrict__ sint,
                                                bf16* __restrict__ Qb, bf16* __restrict__ Kb,
                                                bf16* __restrict__ Vb) {
  __shared__ bf16 As[128 * 64];
  __shared__ bf16 Bs[128 * 64];
  int m0 = blockIdx.y * 128, n0 = blockIdx.x * 128;
  f32x4 acc[4][4] = {};
  gemm_core(xb, WqkvT, CDIM, m0, n0, acc, As, Bs);
  int tid = threadIdx.x, w = tid >> 6, l = tid & 63;
  int wm = (w >> 1) * 64, wn = (w & 1) * 64;
  int which = n0 >> 10;                       // 0=Q 1=K 2=V
  int h = ((n0 + wn) & 1023) >> 6;            // head (wn is 0 or 64 -> full head per wave)
  bf16* Out = which == 0 ? Qb : (which == 1 ? Kb : Vb);
  if (which < 2) {
    float sc = (which == 0) ? QSCALE : 1.0f;
    // RoPE: pair (d, d+32) lives in (acc[i][j], acc[i][j+2]) of the same lane
#pragma unroll
    for (int i = 0; i < 4; ++i)
#pragma unroll
      for (int r = 0; r < 4; ++r) {
        int m = m0 + wm + i * 16 + (l >> 4) * 4 + r;
        int b = m >> 11, t = m & 2047;
        size_t base = (((size_t)(b * NH + h)) * TT + t) * HD;
#pragma unroll
        for (int j = 0; j < 2; ++j) {
          int ii = j * 16 + (l & 15);         // d in [0,32)
          float c = cost[t * 32 + ii], s = sint[t * 32 + ii];
          float x1 = acc[i][j][r], x2 = acc[i][j + 2][r];
          Out[base + ii]      = __float2bfloat16((x1 * c - x2 * s) * sc);
          Out[base + ii + 32] = __float2bfloat16((x2 * c + x1 * s) * sc);
        }
      }
  } else {
#pragma unroll
    for (int i = 0; i < 4; ++i)
#pragma unroll
      for (int r = 0; r < 4; ++r) {
        int m = m0 + wm + i * 16 + (l >> 4) * 4 + r;
        int b = m >> 11, t = m & 2047;
        size_t base = (((size_t)(b * NH + h)) * TT + t) * HD;
#pragma unroll
        for (int j = 0; j < 4; ++j)
          Out[base + ((j * 16 + (l & 15)))] = __float2bfloat16(acc[i][j][r]);
      }
  }
}

// Out GEMM: O[4096][1024] @ Wout + bout -> out fp32
__global__ __launch_bounds__(256) void out_gemm(const bf16* __restrict__ Ob,
                                                const bf16* __restrict__ WoutT,
                                                const float* __restrict__ bout,
                                                float* __restrict__ out) {
  __shared__ bf16 As[128 * 64];
  __shared__ bf16 Bs[128 * 64];
  int m0 = blockIdx.y * 128, n0 = blockIdx.x * 128;
  f32x4 acc[4][4] = {};
  gemm_core(Ob, WoutT, CDIM, m0, n0, acc, As, Bs);
  int tid = threadIdx.x, w = tid >> 6, l = tid & 63;
  int wm = (w >> 1) * 64, wn = (w & 1) * 64;
#pragma unroll
  for (int i = 0; i < 4; ++i)
#pragma unroll
    for (int j = 0; j < 4; ++j)
#pragma unroll
      for (int r = 0; r < 4; ++r) {
        int m = m0 + wm + i * 16 + (l >> 4) * 4 + r;
        int n = n0 + wn + j * 16 + (l & 15);
        out[(size_t)m * CDIM + n] = acc[i][j][r] + bout[n];
      }
}

// ---------------- flash attention (swapped QK^T, in-register P, QBLK=128) ----------------
// R10 structure; ONLY delta: QBLK 64->128 (each wave 32 q-rows as 2 mfma-groups m=0,1).
// kf/vb LDS fragments are read ONCE and reused for both m -> K/V LDS-read and
// staging traffic per unit compute halved (was ~82% of LDS-BW bound).
// Q tile (16KB) staged in two 64-row passes through Ks. Grid (16,32).
#define VP 68  // padded V row stride (elements)
__global__ __launch_bounds__(256) void attn(const bf16* __restrict__ Q,
                                            const bf16* __restrict__ K,
                                            const bf16* __restrict__ VT,
                                            bf16* __restrict__ O) {
  __shared__ bf16 Ks[64 * 64];      // 8KB, swizzled (holds Q tile groups first)
  __shared__ bf16 Vs[64 * VP];      // 8.5KB, linear + padded
  int bh = blockIdx.y, q0 = blockIdx.x * 128;
  int tid = threadIdx.x, w = tid >> 6, l = tid & 63;
  int g = l >> 4, qi = l & 15;

  const bf16* Qg = Q + ((size_t)bh * TT + q0) * HD;
  const bf16* Kg = K + (size_t)bh * TT * HD;
  const bf16* Vg = VT + (size_t)bh * TT * HD;  // [64][T]

  // stage Q tile [128][64] in two 64-row passes; waves 0,1 own rows 0..63,
  // waves 2,3 own rows 64..127 (wave w handles q = w*32 + m*16 + qi).
  short8 aq[2][2];
#pragma unroll
  for (int pass = 0; pass < 2; ++pass) {
#pragma unroll
    for (int it = 0; it < 2; ++it) {
      int ci = it * 256 + tid, r = ci >> 3, cc = ci & 7;
      gll16(Qg + (size_t)(pass * 64 + r) * HD + (cc ^ (r & 7)) * 8,
            &Ks[0] + (it * 256 + w * 64) * 8);
    }
    __syncthreads();
    if ((w >> 1) == pass) {
      int wl = w & 1;  // wave index within this pass
#pragma unroll
      for (int m = 0; m < 2; ++m)
#pragma unroll
        for (int c = 0; c < 2; ++c) {
          int row = wl * 32 + m * 16 + qi;
          int colE = c * 32 + g * 8;
          aq[m][c] = *(const short8*)(&Ks[row * 64 + (colE ^ ((row & 7) << 3))]);
        }
    }
    __syncthreads();
  }

  f32x4 oacc[2][4] = {};
  float lsum[2] = {0.f, 0.f};

  for (int kt = 0; kt < TT; kt += 64) {
    // stage K tile via gll16; V tile via reg -> padded LDS
    uint4 vreg[2];
#pragma unroll
    for (int it = 0; it < 2; ++it) {
      int ci = it * 256 + tid, r = ci >> 3, cc = ci & 7;
      gll16(Kg + (size_t)(kt + r) * HD + (cc ^ (r & 7)) * 8, &Ks[0] + (it * 256 + w * 64) * 8);
      vreg[it] = *(const uint4*)(Vg + (size_t)r * TT + kt + cc * 8);
    }
#pragma unroll
    for (int it = 0; it < 2; ++it) {
      int ci = it * 256 + tid, r = ci >> 3, cc = ci & 7;
      *(uint4*)(&Vs[r * VP + cc * 8]) = vreg[it];
    }
    __syncthreads();

    // S^T = K Q^T for both m-groups; kf read once, reused
    short8 kf[4][2];
#pragma unroll
    for (int kn = 0; kn < 4; ++kn)
#pragma unroll
      for (int c = 0; c < 2; ++c) {
        int row = kn * 16 + qi;
        int colE = c * 32 + g * 8;
        kf[kn][c] = *(const short8*)(&Ks[row * 64 + (colE ^ ((row & 7) << 3))]);
      }
    f32x4 s[2][4] = {};
#pragma unroll
    for (int m = 0; m < 2; ++m)
#pragma unroll
      for (int kn = 0; kn < 4; ++kn)
#pragma unroll
        for (int c = 0; c < 2; ++c)
          s[m][kn] = mfma_bf16(kf[kn][c], aq[m][c], s[m][kn]);

    // p = exp2(s) in-register; pack to bf16 pairs
    uint32_t wlo[2][4], whi[2][4];
#pragma unroll
    for (int m = 0; m < 2; ++m)
#pragma unroll
      for (int kn = 0; kn < 4; ++kn) {
        float p0 = exp2_fast(s[m][kn][0]);
        float p1 = exp2_fast(s[m][kn][1]);
        float p2 = exp2_fast(s[m][kn][2]);
        float p3 = exp2_fast(s[m][kn][3]);
        lsum[m] += (p0 + p1) + (p2 + p3);
        wlo[m][kn] = pkbf16(p0, p1);
        whi[m][kn] = pkbf16(p2, p3);
      }

    // O += P V with permuted depth: slot (c,g,j) -> k = 32c + 16*(j>=4) + 4g + (j&3)
    // vb read once per (c,dn), reused for both m
#pragma unroll
    for (int c = 0; c < 2; ++c) {
      union { short8 s8; uint32_t u[4]; } pa[2];
#pragma unroll
      for (int m = 0; m < 2; ++m) {
        pa[m].u[0] = wlo[m][2 * c];     pa[m].u[1] = whi[m][2 * c];
        pa[m].u[2] = wlo[m][2 * c + 1]; pa[m].u[3] = whi[m][2 * c + 1];
      }
#pragma unroll
      for (int dn = 0; dn < 4; ++dn) {
        int row = dn * 16 + qi;           // d-row of Vs
        int e1 = c * 32 + g * 4;
        uint2 v0 = *(const uint2*)(&Vs[row * VP + e1]);
        uint2 v1 = *(const uint2*)(&Vs[row * VP + e1 + 16]);
        union { short8 s8; uint32_t u[4]; } vb;
        vb.u[0] = v0.x; vb.u[1] = v0.y; vb.u[2] = v1.x; vb.u[3] = v1.y;
#pragma unroll
        for (int m = 0; m < 2; ++m)
          oacc[m][dn] = mfma_bf16(pa[m].s8, vb.s8, oacc[m][dn]);
      }
    }
    __syncthreads();
  }

  // full row-sums: combine the 4 g-groups per m
  float tot[2];
#pragma unroll
  for (int m = 0; m < 2; ++m) {
    float t = lsum[m];
    t += __shfl_xor(t, 16, 64);
    t += __shfl_xor(t, 32, 64);
    tot[m] = t;
  }

  // epilogue: oacc[m][dn][r] = O[q = w*32+m*16+4g+r][d = dn*16+qi]
  int b = bh >> 4, hh = bh & 15;
#pragma unroll
  for (int m = 0; m < 2; ++m)
#pragma unroll
    for (int r = 0; r < 4; ++r) {
      float lq = __shfl(tot[m], g * 4 + r, 64);  // lane (4g+r) holds total for q=4g+r
      float inv = 1.0f / lq;
      int t = q0 + w * 32 + m * 16 + g * 4 + r;
      bf16* Orow = O + ((size_t)(b * TT + t)) * CDIM + hh * HD;
#pragma unroll
      for (int dn = 0; dn < 4; ++dn)
        Orow[dn * 16 + qi] = __float2bfloat16(oacc[m][dn][r] * inv);
    }
}

// ---------------- launcher ----------------

extern "C" void kernel_launch(void* const* d_in, const int* in_sizes, int n_in,
                              void* d_out, int out_size, void* d_ws, size_t ws_size,
                              hipStream_t stream) {
  const float* x    = (const float*)d_in[0];
  const float* Wqkv = (const float*)d_in[1];
  const float* Wout = (const float*)d_in[2];
  const float* bout = (const float*)d_in[3];
  float* out = (float*)d_out;

  char* ws = (char*)d_ws;
  bf16* xb     = (bf16*)(ws);                    // 8 MB (reused as O after attn)
  bf16* WqkvT  = (bf16*)(ws + 8388608);          // 6 MB
  bf16* WoutT  = (bf16*)(ws + 14680064);         // 2 MB
  bf16* Qb     = (bf16*)(ws + 16777216);         // 8 MB
  bf16* Kb     = (bf16*)(ws + 25165824);         // 8 MB
  bf16* Vb     = (bf16*)(ws + 33554432);         // 8 MB
  bf16* VTb    = (bf16*)(ws + 41943040);         // 8 MB
  float* cost  = (float*)(ws + 50331648);        // 256 KB
  float* sint  = (float*)(ws + 50593792);        // 256 KB
  bf16* Ob     = xb;                             // reuse

  cvt_f32_to_bf16<<<2048, 256, 0, stream>>>(x, xb, BT * CDIM);
  transpose_to_bf16<<<dim3(96, 32), dim3(32, 8), 0, stream>>>(Wqkv, WqkvT, CDIM, N3);
  transpose_to_bf16<<<dim3(32, 32), dim3(32, 8), 0, stream>>>(Wout, WoutT, CDIM, CDIM);
  rope_table<<<256, 256, 0, stream>>>(cost, sint);
  qkv_gemm<<<dim3(24, 32), 256, 0, stream>>>(xb, WqkvT, cost, sint, Qb, Kb, Vb);
  transpose_v<<<dim3(64, 2, 32), dim3(32, 8), 0, stream>>>(Vb, VTb);
  attn<<<dim3(16, 32), 256, 0, stream>>>(Qb, Kb, VTb, Ob);
  out_gemm<<<dim3(8, 32), 256, 0, stream>>>(Ob, WoutT, bout, out);
}